// Round 6
// baseline (86.831 us; speedup 1.0000x reference)
//
#include <hip/hip_runtime.h>
#include <math.h>

#define NROWS  2048
#define VOCAB  50000
#define NQ     (VOCAB / 4)   // 12500 float4 per row
#define SRC_L  400
#define PAD_ID 1
#define HSZ    1024          // hash slots (load factor ~0.4)
#define QCAP   64            // duplicate queue capacity
#define PF     4             // prefetched quads per thread

// Kernel A: one block per row. Stream-first structure:
//   entry: issue src/p_copy reg loads + PF p_gen quads, clear hash (no barrier)
//   phase S: stream whole p_gen row, gen-only argmax (no LDS dependency)
//   phase 1: stage src/pc, hash insert (v -> scatter-add sum), dup queue
//   phase 2: wave 0 resolves duplicate sums (ascending-k exact fold)
//   phase M: iterate occupied hash slots, gather g[v] (L3-hot), merge copy
//            candidates with explicit (==, idx<) tie-break
__global__ __launch_bounds__(256, 8) void pg_row_kernel(
    const float* __restrict__ p_gen,
    const float* __restrict__ p_copy,
    const float* __restrict__ p_switch,
    const int*   __restrict__ tgt,
    const int*   __restrict__ src,
    float* __restrict__ out,        // [0]=loss (kernel B), [1..NROWS]=pred
    float* __restrict__ row_loss)   // ws, NROWS floats
{
    const int row = blockIdx.x;
    const int tid = threadIdx.x;

    const float*  __restrict__ g  = p_gen + (size_t)row * VOCAB;
    const float4* __restrict__ g4 = (const float4*)g;

    __shared__ int      s_src[SRC_L];
    __shared__ float    s_pc [SRC_L];
    __shared__ int      s_key[HSZ];
    __shared__ float    s_val[HSZ];
    __shared__ int      s_qs [QCAP];
    __shared__ int      s_qv [QCAP];
    __shared__ int      s_qn;
    __shared__ float    s_gtv;
    __shared__ float    wv[4];
    __shared__ int      wi[4];
    __shared__ float    wsum[4];

    // ---- issue all small loads + p_gen prefetch up front ----
    const int  base = row * SRC_L;
    const int  j1ok = (tid + 256 < SRC_L);
    const int   rs0 = src[base + tid];
    const float rp0 = p_copy[base + tid];
    int rs1 = 0; float rp1 = 0.0f;
    if (j1ok) { rs1 = src[base + tid + 256]; rp1 = p_copy[base + tid + 256]; }

    float4 pfv[PF];
    #pragma unroll
    for (int k = 0; k < PF; ++k) pfv[k] = g4[tid + (k << 8)];

    const float sw  = p_switch[row];
    const float osw = 1.0f - sw;
    const int   tv  = tgt[row];

    // ---- hash clear (no barrier needed until phase 1) ----
    for (int i = tid; i < HSZ; i += 256) s_key[i] = -1;
    if (tid == 0) s_qn = 0;

    // ---- phase S: stream p_gen, gen-only argmax (pure VALU) ----
    float bestv = -1.0f;            // all scores >= 0
    int   besti = 0x7fffffff;

    #define PG_QUAD(t, vv)                                                      \
    {                                                                           \
        const int b = (t) << 2;                                                 \
        float a;                                                                \
        a = __fmul_rn((vv).x, osw);                                             \
        if (a > bestv) { bestv = a; besti = b;     }                            \
        a = __fmul_rn((vv).y, osw);                                             \
        if (a > bestv) { bestv = a; besti = b + 1; }                            \
        a = __fmul_rn((vv).z, osw);                                             \
        if (a > bestv) { bestv = a; besti = b + 2; }                            \
        a = __fmul_rn((vv).w, osw);                                             \
        if (a > bestv) { bestv = a; besti = b + 3; }                            \
        if (tv >= b && tv < b + 4) {                                            \
            float gt = (vv).x;                                                  \
            if      (tv == b + 1) gt = (vv).y;                                  \
            else if (tv == b + 2) gt = (vv).z;                                  \
            else if (tv == b + 3) gt = (vv).w;                                  \
            s_gtv = gt;                                                         \
        }                                                                       \
    }

    #pragma unroll
    for (int k = 0; k < PF; ++k) { const int t = tid + (k << 8); PG_QUAD(t, pfv[k]) }

    int t = tid + (PF << 8);
    for (; t + 256 < NQ; t += 512) {
        const float4 va = g4[t];
        const float4 vb = g4[t + 256];
        PG_QUAD(t, va)
        PG_QUAD(t + 256, vb)
    }
    if (t < NQ) {
        const float4 vc = g4[t];
        PG_QUAD(t, vc)
    }
    #undef PG_QUAD

    // ---- phase 1: stage src/pc + hash insert from registers ----
    s_src[tid] = rs0; s_pc[tid] = rp0;
    if (j1ok) { s_src[tid + 256] = rs1; s_pc[tid + 256] = rp1; }
    __syncthreads();                 // clears + staging visible

    #pragma unroll 2
    for (int rep = 0; rep < 2; ++rep) {
        if (rep == 1 && !j1ok) break;
        const int   v = rep ? rs1 : rs0;
        const float p = rep ? rp1 : rp0;
        unsigned s = (((unsigned)v) * 2654435761u) >> 22;   // 10 bits
        while (true) {
            const int old = atomicCAS(&s_key[s], -1, v);
            if (old == -1) { s_val[s] = p; break; }          // unique so far
            if (old == v) {                                  // duplicate value
                const int qi = atomicAdd(&s_qn, 1);
                if (qi < QCAP) { s_qs[qi] = (int)s; s_qv[qi] = v; }
                break;
            }
            s = (s + 1) & (HSZ - 1);
        }
    }
    __syncthreads();

    // ---- phase 2: wave 0 resolves duplicates (ascending-k exact fold) ----
    if (tid < 64) {
        int qn = s_qn; if (qn > QCAP) qn = QCAP;
        const int lane = tid;
        for (int q = 0; q < qn; ++q) {
            const int slot = s_qs[q];
            const int v    = s_qv[q];
            float S = 0.0f;
            #pragma unroll
            for (int r = 0; r < 7; ++r) {
                const int k  = (r << 6) + lane;
                const int kk = (k < SRC_L) ? k : 0;
                const bool m = (k < SRC_L) && (s_src[kk] == v);
                const float pk = s_pc[kk];
                unsigned long long mask = __ballot(m);
                while (mask) {
                    const int l = __ffsll((long long)mask) - 1;
                    S = __fadd_rn(S, __shfl(pk, l));
                    mask &= mask - 1;
                }
            }
            if (lane == 0) s_val[slot] = S;
        }
    }
    __syncthreads();

    // ---- phase M: merge copy candidates from occupied hash slots ----
    for (int s = tid; s < HSZ; s += 256) {
        const int v = s_key[s];
        if (v >= 0) {
            const float gv   = g[v];                          // L3-hot gather
            const float cand = __fadd_rn(__fmul_rn(sw, s_val[s]),
                                         __fmul_rn(osw, gv));
            if (cand > bestv || (cand == bestv && v < besti)) {
                bestv = cand; besti = v;
            }
        }
    }

    // ---- target copy-sum partials ----
    float tsum = 0.0f;
    for (int k = tid; k < SRC_L; k += 256)
        if (s_src[k] == tv) tsum += s_pc[k];

    // ---- wave (64-lane) reduction ----
    for (int off = 32; off > 0; off >>= 1) {
        const float ov = __shfl_down(bestv, off);
        const int   oi = __shfl_down(besti, off);
        if (ov > bestv || (ov == bestv && oi < besti)) { bestv = ov; besti = oi; }
        tsum += __shfl_down(tsum, off);
    }

    const int wave = tid >> 6;
    if ((tid & 63) == 0) { wv[wave] = bestv; wi[wave] = besti; wsum[wave] = tsum; }
    __syncthreads();

    if (tid == 0) {
        for (int w = 1; w < 4; ++w) {
            if (wv[w] > bestv || (wv[w] == bestv && wi[w] < besti)) {
                bestv = wv[w]; besti = wi[w];
            }
            tsum += wsum[w];
        }
        out[1 + row] = (float)besti;

        const float ts = __fadd_rn(__fmul_rn(sw, tsum), __fmul_rn(osw, s_gtv));
        row_loss[row] = (tv != PAD_ID) ? logf(ts + 1e-12f) : 0.0f;
    }
}

// Kernel B: reduce row losses -> out[0] = -sum/N
__global__ __launch_bounds__(256) void pg_loss_kernel(
    const float* __restrict__ row_loss,
    float* __restrict__ out)
{
    float s = 0.0f;
    for (int i = threadIdx.x; i < NROWS; i += 256) s += row_loss[i];
    for (int off = 32; off > 0; off >>= 1) s += __shfl_down(s, off);

    __shared__ float wsum[4];
    if ((threadIdx.x & 63) == 0) wsum[threadIdx.x >> 6] = s;
    __syncthreads();
    if (threadIdx.x == 0) {
        const float t = wsum[0] + wsum[1] + wsum[2] + wsum[3];
        out[0] = -t / (float)NROWS;
    }
}

extern "C" void kernel_launch(void* const* d_in, const int* in_sizes, int n_in,
                              void* d_out, int out_size, void* d_ws, size_t ws_size,
                              hipStream_t stream) {
    const float* p_gen    = (const float*)d_in[0];
    const float* p_copy   = (const float*)d_in[1];
    const float* p_switch = (const float*)d_in[2];
    const int*   tgt      = (const int*)d_in[3];
    const int*   src      = (const int*)d_in[4];

    float* out      = (float*)d_out;
    float* row_loss = (float*)d_ws;

    pg_row_kernel<<<NROWS, 256, 0, stream>>>(p_gen, p_copy, p_switch, tgt, src,
                                             out, row_loss);
    pg_loss_kernel<<<1, 256, 0, stream>>>(row_loss, out);
}

// Round 7
// 83.641 us; speedup vs baseline: 1.0381x; 1.0381x over previous
//
#include <hip/hip_runtime.h>
#include <math.h>

#define NROWS  2048
#define VOCAB  50000
#define HALF_V 25000
#define NQH    (HALF_V / 4)  // 6250 quads per half-row
#define SRC_L  400
#define PAD_ID 1
#define NBMH   784           // ceil(25000/32)=782, padded
#define HSZ    512           // hash slots (~200 entries/half -> load 0.4)
#define QCAP   64            // duplicate queue capacity
#define PF     4             // prefetched quads per thread

// Kernel A: TWO blocks per row (half-vocab each) -> 4096 blocks = 2 dispatch
// rounds per CU, so round-2 setup/stream overlaps round-1 tails.
// Per block: entry reg-loads (src/pc + PF p_gen quads) -> clears -> hash/bitmap
// build (in-range values only) -> dup resolve -> bitmap-tested stream with
// inline copy-candidate merge (R5 structure) -> wave/block reduce.
// The half owning tgt computes the row loss. Kernel B combines halves.
__global__ __launch_bounds__(256, 8) void pg_half_kernel(
    const float* __restrict__ p_gen,
    const float* __restrict__ p_copy,
    const float* __restrict__ p_switch,
    const int*   __restrict__ tgt,
    const int*   __restrict__ src,
    float* __restrict__ half_bv,    // ws: 4096 best values
    int*   __restrict__ half_bi,    // ws: 4096 best (global) indices
    float* __restrict__ row_loss)   // ws: 2048 row losses (owning half writes)
{
    const int bid  = blockIdx.x;
    const int row  = bid >> 1;
    const int half = bid & 1;
    const int lo   = half * HALF_V;
    const int tid  = threadIdx.x;

    const float*  __restrict__ g  = p_gen + (size_t)row * VOCAB + lo;
    const float4* __restrict__ g4 = (const float4*)g;

    __shared__ int      s_src[SRC_L];
    __shared__ float    s_pc [SRC_L];
    __shared__ unsigned s_bm [NBMH];
    __shared__ int      s_key[HSZ];
    __shared__ float    s_val[HSZ];
    __shared__ int      s_qs [QCAP];
    __shared__ int      s_qv [QCAP];
    __shared__ int      s_qn;
    __shared__ float    s_gtv;
    __shared__ float    wv[4];
    __shared__ int      wi[4];
    __shared__ float    wsum[4];

    // ---- issue all global loads up front ----
    const int  base = row * SRC_L;
    const int  j1ok = (tid + 256 < SRC_L);
    const int   rs0 = src[base + tid];
    const float rp0 = p_copy[base + tid];
    int rs1 = 0; float rp1 = 0.0f;
    if (j1ok) { rs1 = src[base + tid + 256]; rp1 = p_copy[base + tid + 256]; }

    float4 pfv[PF];
    #pragma unroll
    for (int k = 0; k < PF; ++k) pfv[k] = g4[tid + (k << 8)];

    const float sw   = p_switch[row];
    const float osw  = 1.0f - sw;
    const int   tv   = tgt[row];
    const int   tvl  = tv - lo;                       // local target index
    const bool  own  = ((unsigned)tvl < (unsigned)HALF_V);

    // ---- clears (overlap in-flight loads) ----
    for (int i = tid; i < NBMH; i += 256) s_bm[i] = 0u;
    for (int i = tid; i < HSZ;  i += 256) s_key[i] = -1;
    if (tid == 0) s_qn = 0;

    // ---- stage full src/pc row ----
    s_src[tid] = rs0; s_pc[tid] = rp0;
    if (j1ok) { s_src[tid + 256] = rs1; s_pc[tid + 256] = rp1; }
    __syncthreads();

    // ---- phase 1: bitmap + hash insert (in-range values only) ----
    #pragma unroll 2
    for (int rep = 0; rep < 2; ++rep) {
        if (rep == 1 && !j1ok) break;
        const int   v = rep ? rs1 : rs0;
        const float p = rep ? rp1 : rp0;
        const int  vl = v - lo;
        if ((unsigned)vl < (unsigned)HALF_V) {
            atomicOr(&s_bm[vl >> 5], 1u << (vl & 31));
            unsigned s = (((unsigned)v) * 2654435761u) >> 23;   // 9 bits
            while (true) {
                const int old = atomicCAS(&s_key[s], -1, v);
                if (old == -1) { s_val[s] = p; break; }          // unique so far
                if (old == v) {                                  // duplicate value
                    const int qi = atomicAdd(&s_qn, 1);
                    if (qi < QCAP) { s_qs[qi] = (int)s; s_qv[qi] = v; }
                    break;
                }
                s = (s + 1) & (HSZ - 1);
            }
        }
    }
    __syncthreads();

    // ---- phase 2: wave 0 resolves duplicates (ascending-k exact fold) ----
    if (tid < 64) {
        int qn = s_qn; if (qn > QCAP) qn = QCAP;
        const int lane = tid;
        for (int q = 0; q < qn; ++q) {
            const int slot = s_qs[q];
            const int v    = s_qv[q];
            float S = 0.0f;
            #pragma unroll
            for (int r = 0; r < 7; ++r) {
                const int k  = (r << 6) + lane;
                const int kk = (k < SRC_L) ? k : 0;
                const bool m = (k < SRC_L) && (s_src[kk] == v);
                const float pk = s_pc[kk];
                unsigned long long mask = __ballot(m);
                while (mask) {
                    const int l = __ffsll((long long)mask) - 1;
                    S = __fadd_rn(S, __shfl(pk, l));
                    mask &= mask - 1;
                }
            }
            if (lane == 0) s_val[slot] = S;
        }
    }
    __syncthreads();

    float bestv = -1.0f;            // all scores >= 0
    int   besti = 0x7fffffff;       // global index

    // ---- phase 3: stream this half (prefetched quads first, ascending) ----
    #define PG_ELT(b, i, comp)                                                  \
    {                                                                           \
        const float a = __fmul_rn(comp, osw);                                   \
        if (a > bestv) { bestv = a; besti = lo + (b) + (i); }                   \
        if (m4 & (1u << (i))) {                                                 \
            const int v = lo + (b) + (i);                                       \
            unsigned hs = (((unsigned)v) * 2654435761u) >> 23;                  \
            while (s_key[hs] != v) hs = (hs + 1) & (HSZ - 1);                   \
            const float cand = __fadd_rn(__fmul_rn(sw, s_val[hs]),              \
                                         __fmul_rn(osw, comp));                 \
            if (cand > bestv) { bestv = cand; besti = v; }                      \
        }                                                                       \
    }

    #define PG_QUAD(t, vv)                                                      \
    {                                                                           \
        const int b = (t) << 2;                                                 \
        const unsigned m4 = (s_bm[b >> 5] >> (b & 31)) & 0xFu;                  \
        PG_ELT(b, 0, (vv).x)                                                    \
        PG_ELT(b, 1, (vv).y)                                                    \
        PG_ELT(b, 2, (vv).z)                                                    \
        PG_ELT(b, 3, (vv).w)                                                    \
        if (own && tvl >= b && tvl < b + 4) {                                   \
            float gt = (vv).x;                                                  \
            if      (tvl == b + 1) gt = (vv).y;                                 \
            else if (tvl == b + 2) gt = (vv).z;                                 \
            else if (tvl == b + 3) gt = (vv).w;                                 \
            s_gtv = gt;                                                         \
        }                                                                       \
    }

    #pragma unroll
    for (int k = 0; k < PF; ++k) { const int t = tid + (k << 8); PG_QUAD(t, pfv[k]) }

    int t = tid + (PF << 8);
    for (; t + 256 < NQH; t += 512) {
        const float4 va = g4[t];
        const float4 vb = g4[t + 256];
        PG_QUAD(t, va)
        PG_QUAD(t + 256, vb)
    }
    if (t < NQH) {
        const float4 vc = g4[t];
        PG_QUAD(t, vc)
    }
    #undef PG_QUAD
    #undef PG_ELT

    // ---- target copy-sum partials (same pattern as monolithic version) ----
    float tsum = 0.0f;
    for (int k = tid; k < SRC_L; k += 256)
        if (s_src[k] == tv) tsum += s_pc[k];

    // ---- wave (64-lane) reduction ----
    for (int off = 32; off > 0; off >>= 1) {
        const float ov = __shfl_down(bestv, off);
        const int   oi = __shfl_down(besti, off);
        if (ov > bestv || (ov == bestv && oi < besti)) { bestv = ov; besti = oi; }
        tsum += __shfl_down(tsum, off);
    }

    const int wave = tid >> 6;
    if ((tid & 63) == 0) { wv[wave] = bestv; wi[wave] = besti; wsum[wave] = tsum; }
    __syncthreads();

    if (tid == 0) {
        for (int w = 1; w < 4; ++w) {
            if (wv[w] > bestv || (wv[w] == bestv && wi[w] < besti)) {
                bestv = wv[w]; besti = wi[w];
            }
            tsum += wsum[w];
        }
        half_bv[bid] = bestv;
        half_bi[bid] = besti;

        if (own) {
            const float ts = __fadd_rn(__fmul_rn(sw, tsum), __fmul_rn(osw, s_gtv));
            row_loss[row] = (tv != PAD_ID) ? logf(ts + 1e-12f) : 0.0f;
        }
    }
}

// Kernel B: combine halves -> pred; reduce row losses -> out[0].
__global__ __launch_bounds__(256) void pg_final_kernel(
    const float* __restrict__ half_bv,
    const int*   __restrict__ half_bi,
    const float* __restrict__ row_loss,
    float* __restrict__ out)
{
    float s = 0.0f;
    for (int r = threadIdx.x; r < NROWS; r += 256) {
        const float bv0 = half_bv[2 * r], bv1 = half_bv[2 * r + 1];
        const int   bi0 = half_bi[2 * r], bi1 = half_bi[2 * r + 1];
        // half0 indices all < half1 indices -> equality prefers half0
        out[1 + r] = (float)((bv1 > bv0) ? bi1 : bi0);
        s += row_loss[r];
    }
    for (int off = 32; off > 0; off >>= 1) s += __shfl_down(s, off);

    __shared__ float wsum[4];
    if ((threadIdx.x & 63) == 0) wsum[threadIdx.x >> 6] = s;
    __syncthreads();
    if (threadIdx.x == 0) {
        const float t = wsum[0] + wsum[1] + wsum[2] + wsum[3];
        out[0] = -t / (float)NROWS;
    }
}

extern "C" void kernel_launch(void* const* d_in, const int* in_sizes, int n_in,
                              void* d_out, int out_size, void* d_ws, size_t ws_size,
                              hipStream_t stream) {
    const float* p_gen    = (const float*)d_in[0];
    const float* p_copy   = (const float*)d_in[1];
    const float* p_switch = (const float*)d_in[2];
    const int*   tgt      = (const int*)d_in[3];
    const int*   src      = (const int*)d_in[4];

    float* out      = (float*)d_out;
    float* half_bv  = (float*)d_ws;                                   // 4096 f
    int*   half_bi  = (int*)((char*)d_ws + 4096 * sizeof(float));     // 4096 i
    float* row_loss = (float*)((char*)d_ws + 8192 * sizeof(float));   // 2048 f

    pg_half_kernel<<<2 * NROWS, 256, 0, stream>>>(p_gen, p_copy, p_switch, tgt,
                                                  src, half_bv, half_bi, row_loss);
    pg_final_kernel<<<1, 256, 0, stream>>>(half_bv, half_bi, row_loss, out);
}

// Round 9
// 76.076 us; speedup vs baseline: 1.1414x; 1.0994x over previous
//
#include <hip/hip_runtime.h>
#include <math.h>

#define NROWS  2048
#define VOCAB  50000
#define NQ     (VOCAB / 4)   // 12500 float4 per row
#define SRC_L  400
#define PAD_ID 1
#define NBM    1568          // ceil(50000/32)=1563 dwords, padded
#define HSZ    1024          // hash slots (load factor ~0.4)
#define QCAP   64            // duplicate queue capacity
#define PF     4             // prefetched quads per thread (16 KB/block in flight)

typedef float f4 __attribute__((ext_vector_type(4)));   // builtin-compatible

__device__ __forceinline__ f4 nt_load4(const float* p) {
    return __builtin_nontemporal_load((const f4*)p);
}

// Kernel A: one block per row. R5 structure; p_gen stream uses non-temporal
// loads (zero intra-call reuse -> pure cache-policy experiment).
__global__ __launch_bounds__(256, 8) void pg_row_kernel(
    const float* __restrict__ p_gen,
    const float* __restrict__ p_copy,
    const float* __restrict__ p_switch,
    const int*   __restrict__ tgt,
    const int*   __restrict__ src,
    float* __restrict__ out,        // [0]=loss (kernel B), [1..NROWS]=pred
    float* __restrict__ row_loss)   // ws, NROWS floats
{
    const int row = blockIdx.x;
    const int tid = threadIdx.x;

    const float* __restrict__ g = p_gen + (size_t)row * VOCAB;

    __shared__ int      s_src[SRC_L];
    __shared__ float    s_pc [SRC_L];
    __shared__ unsigned s_bm [NBM];
    __shared__ int      s_key[HSZ];
    __shared__ float    s_val[HSZ];
    __shared__ int      s_qs [QCAP];
    __shared__ int      s_qv [QCAP];
    __shared__ int      s_qn;
    __shared__ float    s_gtv;
    __shared__ float    wv[4];
    __shared__ int      wi[4];
    __shared__ float    wsum[4];

    // ---- issue ALL global loads up front ----
    const int  base = row * SRC_L;
    const int  j1ok = (tid + 256 < SRC_L);
    const int   rs0 = src[base + tid];
    const float rp0 = p_copy[base + tid];
    int rs1 = 0; float rp1 = 0.0f;
    if (j1ok) { rs1 = src[base + tid + 256]; rp1 = p_copy[base + tid + 256]; }

    f4 pfv[PF];
    #pragma unroll
    for (int k = 0; k < PF; ++k) pfv[k] = nt_load4(g + 4 * (tid + (k << 8)));

    const float sw  = p_switch[row];
    const float osw = 1.0f - sw;
    const int   tv  = tgt[row];

    // ---- clears (run under the in-flight loads) ----
    for (int i = tid; i < NBM; i += 256) s_bm[i] = 0u;
    for (int i = tid; i < HSZ; i += 256) s_key[i] = -1;
    if (tid == 0) s_qn = 0;
    __syncthreads();                 // clears done before any phase-1 atomics

    // ---- phase 1: stage src/pc + bitmap/hash insert from registers ----
    s_src[tid] = rs0; s_pc[tid] = rp0;
    if (j1ok) { s_src[tid + 256] = rs1; s_pc[tid + 256] = rp1; }

    #pragma unroll 2
    for (int rep = 0; rep < 2; ++rep) {
        if (rep == 1 && !j1ok) break;
        const int   v = rep ? rs1 : rs0;
        const float p = rep ? rp1 : rp0;
        atomicOr(&s_bm[v >> 5], 1u << (v & 31));
        unsigned s = (((unsigned)v) * 2654435761u) >> 22;   // 10 bits
        while (true) {
            const int old = atomicCAS(&s_key[s], -1, v);
            if (old == -1) { s_val[s] = p; break; }          // unique so far
            if (old == v) {                                  // duplicate value
                const int qi = atomicAdd(&s_qn, 1);
                if (qi < QCAP) { s_qs[qi] = (int)s; s_qv[qi] = v; }
                break;
            }
            s = (s + 1) & (HSZ - 1);
        }
    }
    __syncthreads();

    // ---- phase 2: wave 0 resolves duplicates (ascending-k exact fold) ----
    if (tid < 64) {
        int qn = s_qn; if (qn > QCAP) qn = QCAP;
        const int lane = tid;
        for (int q = 0; q < qn; ++q) {
            const int slot = s_qs[q];
            const int v    = s_qv[q];
            float S = 0.0f;
            #pragma unroll
            for (int r = 0; r < 7; ++r) {
                const int k  = (r << 6) + lane;
                const int kk = (k < SRC_L) ? k : 0;
                const bool m = (k < SRC_L) && (s_src[kk] == v);
                const float pk = s_pc[kk];
                unsigned long long mask = __ballot(m);
                while (mask) {
                    const int l = __ffsll((long long)mask) - 1;
                    S = __fadd_rn(S, __shfl(pk, l));
                    mask &= mask - 1;
                }
            }
            if (lane == 0) s_val[slot] = S;
        }
    }
    __syncthreads();

    float bestv = -1.0f;            // all scores >= 0
    int   besti = 0x7fffffff;

    // ---- phase 3: stream p_gen (nt loads; prefetched quads first) ----
    #define PG_ELT(b, i, comp)                                                  \
    {                                                                           \
        const float a = __fmul_rn(comp, osw);                                   \
        if (a > bestv) { bestv = a; besti = (b) + (i); }                        \
        if (m4 & (1u << (i))) {                                                 \
            const int v = (b) + (i);                                            \
            unsigned hs = (((unsigned)v) * 2654435761u) >> 22;                  \
            while (s_key[hs] != v) hs = (hs + 1) & (HSZ - 1);                   \
            const float cand = __fadd_rn(__fmul_rn(sw, s_val[hs]),              \
                                         __fmul_rn(osw, comp));                 \
            if (cand > bestv) { bestv = cand; besti = v; }                      \
        }                                                                       \
    }

    #define PG_QUAD(t, vv)                                                      \
    {                                                                           \
        const int b = (t) << 2;                                                 \
        const unsigned m4 = (s_bm[b >> 5] >> (b & 31)) & 0xFu;                  \
        PG_ELT(b, 0, (vv).x)                                                    \
        PG_ELT(b, 1, (vv).y)                                                    \
        PG_ELT(b, 2, (vv).z)                                                    \
        PG_ELT(b, 3, (vv).w)                                                    \
        if (tv >= b && tv < b + 4) {                                            \
            float gt = (vv).x;                                                  \
            if      (tv == b + 1) gt = (vv).y;                                  \
            else if (tv == b + 2) gt = (vv).z;                                  \
            else if (tv == b + 3) gt = (vv).w;                                  \
            s_gtv = gt;                                                         \
        }                                                                       \
    }

    #pragma unroll
    for (int k = 0; k < PF; ++k) { const int t = tid + (k << 8); PG_QUAD(t, pfv[k]) }

    int t = tid + (PF << 8);
    for (; t + 256 < NQ; t += 512) {
        const f4 va = nt_load4(g + 4 * t);
        const f4 vb = nt_load4(g + 4 * (t + 256));
        PG_QUAD(t, va)
        PG_QUAD(t + 256, vb)
    }
    if (t < NQ) {
        const f4 vc = nt_load4(g + 4 * t);
        PG_QUAD(t, vc)
    }
    #undef PG_QUAD
    #undef PG_ELT

    // ---- target copy-sum partials ----
    float tsum = 0.0f;
    for (int k = tid; k < SRC_L; k += 256)
        if (s_src[k] == tv) tsum += s_pc[k];

    // ---- wave (64-lane) reduction ----
    for (int off = 32; off > 0; off >>= 1) {
        const float ov = __shfl_down(bestv, off);
        const int   oi = __shfl_down(besti, off);
        if (ov > bestv || (ov == bestv && oi < besti)) { bestv = ov; besti = oi; }
        tsum += __shfl_down(tsum, off);
    }

    const int wave = tid >> 6;
    if ((tid & 63) == 0) { wv[wave] = bestv; wi[wave] = besti; wsum[wave] = tsum; }
    __syncthreads();

    if (tid == 0) {
        for (int w = 1; w < 4; ++w) {
            if (wv[w] > bestv || (wv[w] == bestv && wi[w] < besti)) {
                bestv = wv[w]; besti = wi[w];
            }
            tsum += wsum[w];
        }
        out[1 + row] = (float)besti;

        const float ts = __fadd_rn(__fmul_rn(sw, tsum), __fmul_rn(osw, s_gtv));
        row_loss[row] = (tv != PAD_ID) ? logf(ts + 1e-12f) : 0.0f;
    }
}

// Kernel B: reduce row losses -> out[0] = -sum/N
__global__ __launch_bounds__(256) void pg_loss_kernel(
    const float* __restrict__ row_loss,
    float* __restrict__ out)
{
    float s = 0.0f;
    for (int i = threadIdx.x; i < NROWS; i += 256) s += row_loss[i];
    for (int off = 32; off > 0; off >>= 1) s += __shfl_down(s, off);

    __shared__ float wsum[4];
    if ((threadIdx.x & 63) == 0) wsum[threadIdx.x >> 6] = s;
    __syncthreads();
    if (threadIdx.x == 0) {
        const float t = wsum[0] + wsum[1] + wsum[2] + wsum[3];
        out[0] = -t / (float)NROWS;
    }
}

extern "C" void kernel_launch(void* const* d_in, const int* in_sizes, int n_in,
                              void* d_out, int out_size, void* d_ws, size_t ws_size,
                              hipStream_t stream) {
    const float* p_gen    = (const float*)d_in[0];
    const float* p_copy   = (const float*)d_in[1];
    const float* p_switch = (const float*)d_in[2];
    const int*   tgt      = (const int*)d_in[3];
    const int*   src      = (const int*)d_in[4];

    float* out      = (float*)d_out;
    float* row_loss = (float*)d_ws;

    pg_row_kernel<<<NROWS, 256, 0, stream>>>(p_gen, p_copy, p_switch, tgt, src,
                                             out, row_loss);
    pg_loss_kernel<<<1, 256, 0, stream>>>(row_loss, out);
}

// Round 10
// 74.916 us; speedup vs baseline: 1.1590x; 1.0155x over previous
//
#include <hip/hip_runtime.h>
#include <math.h>

#define NROWS  2048
#define VOCAB  50000
#define NQ     (VOCAB / 4)   // 12500 float4 per row
#define SRC_L  400
#define PAD_ID 1
#define NBM    1568          // ceil(50000/32)=1563 dwords, padded
#define HSZ    1024          // hash slots (load factor ~0.4)
#define QCAP   64            // duplicate queue capacity
#define PF     6             // prefetched quads per thread (24 KB/block in flight)

typedef float f4 __attribute__((ext_vector_type(4)));   // builtin-compatible

__device__ __forceinline__ f4 nt_load4(const float* p) {
    return __builtin_nontemporal_load((const f4*)p);
}

// Kernel A: one block per row. R9 structure (nt-load stream), PF 4 -> 6.
__global__ __launch_bounds__(256, 8) void pg_row_kernel(
    const float* __restrict__ p_gen,
    const float* __restrict__ p_copy,
    const float* __restrict__ p_switch,
    const int*   __restrict__ tgt,
    const int*   __restrict__ src,
    float* __restrict__ out,        // [0]=loss (kernel B), [1..NROWS]=pred
    float* __restrict__ row_loss)   // ws, NROWS floats
{
    const int row = blockIdx.x;
    const int tid = threadIdx.x;

    const float* __restrict__ g = p_gen + (size_t)row * VOCAB;

    __shared__ int      s_src[SRC_L];
    __shared__ float    s_pc [SRC_L];
    __shared__ unsigned s_bm [NBM];
    __shared__ int      s_key[HSZ];
    __shared__ float    s_val[HSZ];
    __shared__ int      s_qs [QCAP];
    __shared__ int      s_qv [QCAP];
    __shared__ int      s_qn;
    __shared__ float    s_gtv;
    __shared__ float    wv[4];
    __shared__ int      wi[4];
    __shared__ float    wsum[4];

    // ---- issue ALL global loads up front ----
    const int  base = row * SRC_L;
    const int  j1ok = (tid + 256 < SRC_L);
    const int   rs0 = src[base + tid];
    const float rp0 = p_copy[base + tid];
    int rs1 = 0; float rp1 = 0.0f;
    if (j1ok) { rs1 = src[base + tid + 256]; rp1 = p_copy[base + tid + 256]; }

    f4 pfv[PF];
    #pragma unroll
    for (int k = 0; k < PF; ++k) pfv[k] = nt_load4(g + 4 * (tid + (k << 8)));

    const float sw  = p_switch[row];
    const float osw = 1.0f - sw;
    const int   tv  = tgt[row];

    // ---- clears (run under the in-flight loads) ----
    for (int i = tid; i < NBM; i += 256) s_bm[i] = 0u;
    for (int i = tid; i < HSZ; i += 256) s_key[i] = -1;
    if (tid == 0) s_qn = 0;
    __syncthreads();                 // clears done before any phase-1 atomics

    // ---- phase 1: stage src/pc + bitmap/hash insert from registers ----
    s_src[tid] = rs0; s_pc[tid] = rp0;
    if (j1ok) { s_src[tid + 256] = rs1; s_pc[tid + 256] = rp1; }

    #pragma unroll 2
    for (int rep = 0; rep < 2; ++rep) {
        if (rep == 1 && !j1ok) break;
        const int   v = rep ? rs1 : rs0;
        const float p = rep ? rp1 : rp0;
        atomicOr(&s_bm[v >> 5], 1u << (v & 31));
        unsigned s = (((unsigned)v) * 2654435761u) >> 22;   // 10 bits
        while (true) {
            const int old = atomicCAS(&s_key[s], -1, v);
            if (old == -1) { s_val[s] = p; break; }          // unique so far
            if (old == v) {                                  // duplicate value
                const int qi = atomicAdd(&s_qn, 1);
                if (qi < QCAP) { s_qs[qi] = (int)s; s_qv[qi] = v; }
                break;
            }
            s = (s + 1) & (HSZ - 1);
        }
    }
    __syncthreads();

    // ---- phase 2: wave 0 resolves duplicates (ascending-k exact fold) ----
    if (tid < 64) {
        int qn = s_qn; if (qn > QCAP) qn = QCAP;
        const int lane = tid;
        for (int q = 0; q < qn; ++q) {
            const int slot = s_qs[q];
            const int v    = s_qv[q];
            float S = 0.0f;
            #pragma unroll
            for (int r = 0; r < 7; ++r) {
                const int k  = (r << 6) + lane;
                const int kk = (k < SRC_L) ? k : 0;
                const bool m = (k < SRC_L) && (s_src[kk] == v);
                const float pk = s_pc[kk];
                unsigned long long mask = __ballot(m);
                while (mask) {
                    const int l = __ffsll((long long)mask) - 1;
                    S = __fadd_rn(S, __shfl(pk, l));
                    mask &= mask - 1;
                }
            }
            if (lane == 0) s_val[slot] = S;
        }
    }
    __syncthreads();

    float bestv = -1.0f;            // all scores >= 0
    int   besti = 0x7fffffff;

    // ---- phase 3: stream p_gen (nt loads; prefetched quads first) ----
    #define PG_ELT(b, i, comp)                                                  \
    {                                                                           \
        const float a = __fmul_rn(comp, osw);                                   \
        if (a > bestv) { bestv = a; besti = (b) + (i); }                        \
        if (m4 & (1u << (i))) {                                                 \
            const int v = (b) + (i);                                            \
            unsigned hs = (((unsigned)v) * 2654435761u) >> 22;                  \
            while (s_key[hs] != v) hs = (hs + 1) & (HSZ - 1);                   \
            const float cand = __fadd_rn(__fmul_rn(sw, s_val[hs]),              \
                                         __fmul_rn(osw, comp));                 \
            if (cand > bestv) { bestv = cand; besti = v; }                      \
        }                                                                       \
    }

    #define PG_QUAD(t, vv)                                                      \
    {                                                                           \
        const int b = (t) << 2;                                                 \
        const unsigned m4 = (s_bm[b >> 5] >> (b & 31)) & 0xFu;                  \
        PG_ELT(b, 0, (vv).x)                                                    \
        PG_ELT(b, 1, (vv).y)                                                    \
        PG_ELT(b, 2, (vv).z)                                                    \
        PG_ELT(b, 3, (vv).w)                                                    \
        if (tv >= b && tv < b + 4) {                                            \
            float gt = (vv).x;                                                  \
            if      (tv == b + 1) gt = (vv).y;                                  \
            else if (tv == b + 2) gt = (vv).z;                                  \
            else if (tv == b + 3) gt = (vv).w;                                  \
            s_gtv = gt;                                                         \
        }                                                                       \
    }

    #pragma unroll
    for (int k = 0; k < PF; ++k) { const int t = tid + (k << 8); PG_QUAD(t, pfv[k]) }

    int t = tid + (PF << 8);
    for (; t + 256 < NQ; t += 512) {
        const f4 va = nt_load4(g + 4 * t);
        const f4 vb = nt_load4(g + 4 * (t + 256));
        PG_QUAD(t, va)
        PG_QUAD(t + 256, vb)
    }
    if (t < NQ) {
        const f4 vc = nt_load4(g + 4 * t);
        PG_QUAD(t, vc)
    }
    #undef PG_QUAD
    #undef PG_ELT

    // ---- target copy-sum partials ----
    float tsum = 0.0f;
    for (int k = tid; k < SRC_L; k += 256)
        if (s_src[k] == tv) tsum += s_pc[k];

    // ---- wave (64-lane) reduction ----
    for (int off = 32; off > 0; off >>= 1) {
        const float ov = __shfl_down(bestv, off);
        const int   oi = __shfl_down(besti, off);
        if (ov > bestv || (ov == bestv && oi < besti)) { bestv = ov; besti = oi; }
        tsum += __shfl_down(tsum, off);
    }

    const int wave = tid >> 6;
    if ((tid & 63) == 0) { wv[wave] = bestv; wi[wave] = besti; wsum[wave] = tsum; }
    __syncthreads();

    if (tid == 0) {
        for (int w = 1; w < 4; ++w) {
            if (wv[w] > bestv || (wv[w] == bestv && wi[w] < besti)) {
                bestv = wv[w]; besti = wi[w];
            }
            tsum += wsum[w];
        }
        out[1 + row] = (float)besti;

        const float ts = __fadd_rn(__fmul_rn(sw, tsum), __fmul_rn(osw, s_gtv));
        row_loss[row] = (tv != PAD_ID) ? logf(ts + 1e-12f) : 0.0f;
    }
}

// Kernel B: reduce row losses -> out[0] = -sum/N
__global__ __launch_bounds__(256) void pg_loss_kernel(
    const float* __restrict__ row_loss,
    float* __restrict__ out)
{
    float s = 0.0f;
    for (int i = threadIdx.x; i < NROWS; i += 256) s += row_loss[i];
    for (int off = 32; off > 0; off >>= 1) s += __shfl_down(s, off);

    __shared__ float wsum[4];
    if ((threadIdx.x & 63) == 0) wsum[threadIdx.x >> 6] = s;
    __syncthreads();
    if (threadIdx.x == 0) {
        const float t = wsum[0] + wsum[1] + wsum[2] + wsum[3];
        out[0] = -t / (float)NROWS;
    }
}

extern "C" void kernel_launch(void* const* d_in, const int* in_sizes, int n_in,
                              void* d_out, int out_size, void* d_ws, size_t ws_size,
                              hipStream_t stream) {
    const float* p_gen    = (const float*)d_in[0];
    const float* p_copy   = (const float*)d_in[1];
    const float* p_switch = (const float*)d_in[2];
    const int*   tgt      = (const int*)d_in[3];
    const int*   src      = (const int*)d_in[4];

    float* out      = (float*)d_out;
    float* row_loss = (float*)d_ws;

    pg_row_kernel<<<NROWS, 256, 0, stream>>>(p_gen, p_copy, p_switch, tgt, src,
                                             out, row_loss);
    pg_loss_kernel<<<1, 256, 0, stream>>>(row_loss, out);
}